// Round 10
// baseline (242.658 us; speedup 1.0000x reference)
//
#include <hip/hip_runtime.h>
#include <hip/hip_bf16.h>

#define TPB  256
#define NBLK 2048

typedef float f2 __attribute__((ext_vector_type(2)));

static __device__ __forceinline__ f2 mk2(float a, float b) { f2 r; r.x = a; r.y = b; return r; }

// ws layout (fp32): W[grp*256 + j*32 + k] = w1[j][grp*32+k], grp 0:u*m 1:u 2:m
// W[768+j]=b1[j]; W[776+j]=w2[j]; W[784]=b2   (k-contiguous within each j)
__global__ void prep_kernel(const float* __restrict__ w1, const float* __restrict__ b1,
                            const float* __restrict__ w2, const float* __restrict__ b2,
                            float* __restrict__ W) {
    int t = threadIdx.x;
    for (int i = t; i < 768; i += TPB) {
        int grp = i >> 8, r = i & 255, j = r >> 5, k = r & 31;
        W[i] = w1[j * 96 + grp * 32 + k];
    }
    if (t < 8) W[768 + t] = b1[t];
    if (t < 8) W[776 + t] = w2[t];
    if (t == 0) W[784]    = b2[0];
}

// 8 lanes per element: lane c = l&7 owns k-chunk [4c..4c+3] (one 16 B load of
// each row). No LDS storage, no transpose, no global_load_lds DMA. Butterfly
// shfl_xor over the 8-lane group completes the K-reduction.
__global__ __launch_bounds__(TPB, 3) void mf_kernel(
    const int* __restrict__ users, const int* __restrict__ movies,
    const float4* __restrict__ uemb,   // fp32 [1e6][32] -> [1e6][8] float4
    const float4* __restrict__ memb,   // fp32 [1e5][32]
    const float* __restrict__ W,
    float* __restrict__ out, int n) {

    const int t    = threadIdx.x;
    const int lane = t & 63;
    const int c    = lane & 7;       // k-chunk within the row
    const int g    = lane >> 3;      // element-group within the wave
    const int wid  = blockIdx.x * (TPB >> 6) + (t >> 6);
    const int nw   = NBLK * (TPB >> 6);

    // Loop-invariant per-lane weights: 24 x float4 = 96 VGPRs.
    float4 WAq[8], WBq[8], WCq[8];
#pragma unroll
    for (int j = 0; j < 8; ++j) {
        WAq[j] = *(const float4*)(W +       j * 32 + 4 * c);
        WBq[j] = *(const float4*)(W + 256 + j * 32 + 4 * c);
        WCq[j] = *(const float4*)(W + 512 + j * 32 + 4 * c);
    }
    // Wave-uniform epilogue constants (scalar loads / SGPRs).
    float b1j[8], w2j[8];
#pragma unroll
    for (int j = 0; j < 8; ++j) { b1j[j] = W[768 + j]; w2j[j] = W[776 + j]; }
    const float b2 = W[784];

    const int n8 = (n + 7) >> 3;
    for (int o = wid; o < n8; o += nw) {
        int e  = o * 8 + g;
        int ec = (e < n) ? e : (n - 1);
        int ui = users[ec];          // same addr across the 8 lanes of a group
        int mi = movies[ec];
        float4 u4 = uemb[(size_t)ui * 8 + c];   // 8 rows x 128 B per instr
        float4 m4 = memb[(size_t)mi * 8 + c];

        f2 u01 = mk2(u4.x, u4.y), u23 = mk2(u4.z, u4.w);
        f2 m01 = mk2(m4.x, m4.y), m23 = mk2(m4.z, m4.w);
        f2 p01 = u01 * m01,       p23 = u23 * m23;   // v_pk_mul_f32

        float h[8];
#pragma unroll
        for (int j = 0; j < 8; ++j) {
            f2 a = mk2(0.0f, 0.0f);
            a = __builtin_elementwise_fma(p01, mk2(WAq[j].x, WAq[j].y), a);
            a = __builtin_elementwise_fma(p23, mk2(WAq[j].z, WAq[j].w), a);
            a = __builtin_elementwise_fma(u01, mk2(WBq[j].x, WBq[j].y), a);
            a = __builtin_elementwise_fma(u23, mk2(WBq[j].z, WBq[j].w), a);
            a = __builtin_elementwise_fma(m01, mk2(WCq[j].x, WCq[j].y), a);
            a = __builtin_elementwise_fma(m23, mk2(WCq[j].z, WCq[j].w), a);
            h[j] = a.x + a.y;
        }

        // Sum partials across the 8-lane group (masks 1,2,4 stay in-group).
#pragma unroll
        for (int j = 0; j < 8; ++j) h[j] += __shfl_xor(h[j], 1, 64);
#pragma unroll
        for (int j = 0; j < 8; ++j) h[j] += __shfl_xor(h[j], 2, 64);
#pragma unroll
        for (int j = 0; j < 8; ++j) h[j] += __shfl_xor(h[j], 4, 64);

        float z = b2;
#pragma unroll
        for (int j = 0; j < 8; ++j)
            z = fmaf(fmaxf(h[j] + b1j[j], 0.0f), w2j[j], z);

        float r = 1.0f / (1.0f + __expf(-z));
        if (c == 0 && e < n) out[e] = r;
    }
}

extern "C" void kernel_launch(void* const* d_in, const int* in_sizes, int n_in,
                              void* d_out, int out_size, void* d_ws, size_t ws_size,
                              hipStream_t stream) {
    const int* users   = (const int*)d_in[0];
    const int* movies  = (const int*)d_in[1];
    const float4* uemb = (const float4*)d_in[2];   // fp32 [1e6, 32]
    const float4* memb = (const float4*)d_in[3];   // fp32 [1e5, 32]
    const float* w1    = (const float*)d_in[4];    // fp32 [8, 96]
    const float* b1    = (const float*)d_in[5];    // fp32 [8]
    const float* w2    = (const float*)d_in[6];    // fp32 [1, 8]
    const float* b2    = (const float*)d_in[7];    // fp32 [1]
    float* ws  = (float*)d_ws;
    float* out = (float*)d_out;

    int n = in_sizes[0];

    prep_kernel<<<1, TPB, 0, stream>>>(w1, b1, w2, b2, ws);
    mf_kernel<<<NBLK, TPB, 0, stream>>>(users, movies, uemb, memb, ws, out, n);
}